// Round 2
// baseline (91.995 us; speedup 1.0000x reference)
//
#include <hip/hip_runtime.h>

// Problem constants (from reference)
#define SOM_M 256
#define SOM_N 256
#define SOM_DIM 512
#define SOM_ROWS (SOM_M * SOM_N)          // 65536
#define SOM_ELEMS (SOM_ROWS * SOM_DIM)    // 33554432

typedef float f32x4 __attribute__((ext_vector_type(4)));
typedef float f32x2 __attribute__((ext_vector_type(2)));

// ---------------- Kernel 1: BMU argmin via packed atomicMin ----------------
// One wave (64 lanes) per row; lane loads 8 floats (2x float4), butterfly
// reduce sum of squared diffs; block does one atomicMin of (dist|idx) u64.
// dist >= 0 so float bits are monotone as u32; equal dist -> smaller row wins,
// matching jnp.argmin first-occurrence semantics.
__global__ __launch_bounds__(256) void som_bmu(
    const float* __restrict__ w, const float* __restrict__ in,
    unsigned long long* __restrict__ best) {
  __shared__ float s_in[SOM_DIM];
  for (int i = threadIdx.x; i < SOM_DIM; i += 256) s_in[i] = in[i];
  __syncthreads();

  const int wave = threadIdx.x >> 6;
  const int lane = threadIdx.x & 63;
  const int globalWave = blockIdx.x * 4 + wave;
  const int nWaves = gridDim.x * 4;

  float bd = 3.4e38f;
  int bi = SOM_ROWS;

  const f32x4* in4 = (const f32x4*)s_in;
  for (int row = globalWave; row < SOM_ROWS; row += nWaves) {
    const f32x4* wr = (const f32x4*)(w + (size_t)row * SOM_DIM);
    float acc = 0.f;
#pragma unroll
    for (int k = 0; k < 2; ++k) {
      f32x4 wv = wr[lane + 64 * k];
      f32x4 iv = in4[lane + 64 * k];
      f32x4 d = wv - iv;
      acc += d.x * d.x + d.y * d.y + d.z * d.z + d.w * d.w;
    }
#pragma unroll
    for (int off = 32; off; off >>= 1) acc += __shfl_xor(acc, off, 64);
    // rows visited in increasing order per wave -> strict < keeps first min
    if (acc < bd) { bd = acc; bi = row; }
  }

  unsigned long long pk =
      ((unsigned long long)__float_as_uint(bd) << 32) | (unsigned int)bi;

  __shared__ unsigned long long sp[4];
  if (lane == 0) sp[wave] = pk;
  __syncthreads();
  if (threadIdx.x == 0) {
    unsigned long long m = sp[0];
#pragma unroll
    for (int k = 1; k < 4; ++k) m = (sp[k] < m) ? sp[k] : m;
    atomicMin(best, m);  // device-scope by default
  }
}

// ---------------- Kernel 2: weight update (+ bmu_loc write) ----------------
// new_w = w + alpha_op * exp(-bmu_dist_sq / sigma_op^2) * (in - w)
// Output stores are non-temporal: never re-read, keep weights resident in L3.
__global__ __launch_bounds__(256) void som_update(
    const float* __restrict__ w, const float* __restrict__ in,
    const int* __restrict__ epoch_p,
    const unsigned long long* __restrict__ best,
    float* __restrict__ out /* d_out base */) {
  const unsigned long long pk = *best;
  const int bidx = (int)(unsigned int)(pk & 0xFFFFFFFFull);
  const int br = bidx >> 8;   // N = 256
  const int bc = bidx & 255;

  if (blockIdx.x == 0 && threadIdx.x == 0) {
    out[0] = (float)br;
    out[1] = (float)bc;
  }

  const float lr = 1.0f - (float)epoch_p[0] / 100.0f;
  const float alpha_op = 0.3f * lr;
  const float sigma_op = 128.0f * lr;
  const float inv_s2 = 1.0f / (sigma_op * sigma_op);

  const f32x4* w4 = (const f32x4*)w;
  const f32x4* in4 = (const f32x4*)in;
  f32x2* o2 = (f32x2*)(out + 2);  // 8B-aligned -> float2 stores

  const int total4 = SOM_ELEMS / 4;  // 8388608
  const int stride = gridDim.x * blockDim.x;
  for (int i = blockIdx.x * blockDim.x + threadIdx.x; i < total4; i += stride) {
    const int elem = i << 2;
    const int row = elem >> 9;          // DIM = 512
    const int c4 = (elem & 511) >> 2;   // float4 index within row
    const int rr = (row >> 8) - br;
    const int cc = (row & 255) - bc;
    const float d2 = (float)(rr * rr + cc * cc);
    const float mult = alpha_op * __expf(-d2 * inv_s2);

    f32x4 wv = w4[i];
    f32x4 iv = in4[c4];
    f32x4 r = wv + mult * (iv - wv);
    f32x2 a; a.x = r.x; a.y = r.y;
    f32x2 b; b.x = r.z; b.y = r.w;
    __builtin_nontemporal_store(a, &o2[2 * i]);
    __builtin_nontemporal_store(b, &o2[2 * i + 1]);
  }
}

extern "C" void kernel_launch(void* const* d_in, const int* in_sizes, int n_in,
                              void* d_out, int out_size, void* d_ws, size_t ws_size,
                              hipStream_t stream) {
  const float* input_vector = (const float*)d_in[0];
  const float* weights = (const float*)d_in[1];
  const int* epoch = (const int*)d_in[2];
  float* out = (float*)d_out;

  unsigned long long* best = (unsigned long long*)d_ws;

  // init packed argmin to +inf|maxidx (0xFF... > any finite packed value)
  hipMemsetAsync(best, 0xFF, 8, stream);
  som_bmu<<<2048, 256, 0, stream>>>(weights, input_vector, best);
  som_update<<<2048, 256, 0, stream>>>(weights, input_vector, epoch, best, out);
}

// Round 3
// 70.860 us; speedup vs baseline: 1.2983x; 1.2983x over previous
//
#include <hip/hip_runtime.h>

// Problem constants (from reference)
#define SOM_M 256
#define SOM_N 256
#define SOM_DIM 512
#define SOM_ROWS (SOM_M * SOM_N)          // 65536
#define SOM_ELEMS (SOM_ROWS * SOM_DIM)    // 33554432
#define NB 2048                           // blocks for both kernels

typedef float f32x4 __attribute__((ext_vector_type(4)));
typedef float f32x2 __attribute__((ext_vector_type(2)));

// ---------------- Kernel 1: per-block BMU partial argmin ----------------
// One wave (64 lanes) per row; lane loads 8 floats (2x float4), butterfly
// reduce sum of squared diffs; block writes packed (dist|idx) u64 partial.
// dist >= 0 so float bits are monotone as u32; equal dist -> smaller row
// wins, matching jnp.argmin first-occurrence semantics.
__global__ __launch_bounds__(256) void som_bmu_partial(
    const float* __restrict__ w, const float* __restrict__ in,
    unsigned long long* __restrict__ part) {
  __shared__ float s_in[SOM_DIM];
  for (int i = threadIdx.x; i < SOM_DIM; i += 256) s_in[i] = in[i];
  __syncthreads();

  const int wave = threadIdx.x >> 6;
  const int lane = threadIdx.x & 63;
  const int globalWave = blockIdx.x * 4 + wave;
  const int nWaves = NB * 4;

  float bd = 3.4e38f;
  int bi = SOM_ROWS;

  const f32x4* in4 = (const f32x4*)s_in;
  for (int row = globalWave; row < SOM_ROWS; row += nWaves) {
    const f32x4* wr = (const f32x4*)(w + (size_t)row * SOM_DIM);
    float acc = 0.f;
#pragma unroll
    for (int k = 0; k < 2; ++k) {
      f32x4 wv = wr[lane + 64 * k];
      f32x4 iv = in4[lane + 64 * k];
      f32x4 d = wv - iv;
      acc += d.x * d.x + d.y * d.y + d.z * d.z + d.w * d.w;
    }
#pragma unroll
    for (int off = 32; off; off >>= 1) acc += __shfl_xor(acc, off, 64);
    // rows visited in increasing order per wave -> strict < keeps first min
    if (acc < bd) { bd = acc; bi = row; }
  }

  unsigned long long pk =
      ((unsigned long long)__float_as_uint(bd) << 32) | (unsigned int)bi;

  __shared__ unsigned long long sp[4];
  if (lane == 0) sp[wave] = pk;
  __syncthreads();
  if (threadIdx.x == 0) {
    unsigned long long m = sp[0];
#pragma unroll
    for (int k = 1; k < 4; ++k) m = (sp[k] < m) ? sp[k] : m;
    part[blockIdx.x] = m;
  }
}

// ---------------- Kernel 2: inline final reduce + weight update ----------------
// Each block first min-reduces the NB packed partials (L2-resident, ~16KB),
// then: new_w = w + alpha_op * exp(-bmu_dist_sq / sigma_op^2) * (in - w)
__global__ __launch_bounds__(256) void som_update(
    const float* __restrict__ w, const float* __restrict__ in,
    const int* __restrict__ epoch_p,
    const unsigned long long* __restrict__ part,
    float* __restrict__ out /* d_out base */) {
  // --- final argmin reduce (all blocks, redundant but cheap) ---
  __shared__ unsigned long long sp[256];
  unsigned long long m = ~0ull;
  for (int i = threadIdx.x; i < NB; i += 256) {
    unsigned long long v = part[i];
    m = (v < m) ? v : m;
  }
  sp[threadIdx.x] = m;
  __syncthreads();
  for (int s = 128; s; s >>= 1) {
    if ((int)threadIdx.x < s) {
      if (sp[threadIdx.x + s] < sp[threadIdx.x]) sp[threadIdx.x] = sp[threadIdx.x + s];
    }
    __syncthreads();
  }
  const int bidx = (int)(unsigned int)(sp[0] & 0xFFFFFFFFull);
  const int br = bidx >> 8;   // N = 256
  const int bc = bidx & 255;

  if (blockIdx.x == 0 && threadIdx.x == 0) {
    out[0] = (float)br;
    out[1] = (float)bc;
  }

  const float lr = 1.0f - (float)epoch_p[0] / 100.0f;
  const float alpha_op = 0.3f * lr;
  const float sigma_op = 128.0f * lr;
  const float inv_s2 = 1.0f / (sigma_op * sigma_op);

  const f32x4* w4 = (const f32x4*)w;
  const f32x4* in4 = (const f32x4*)in;
  f32x2* o2 = (f32x2*)(out + 2);  // 8B-aligned -> float2 stores

  const int total4 = SOM_ELEMS / 4;  // 8388608
  const int stride = NB * 256;
  for (int i = blockIdx.x * 256 + threadIdx.x; i < total4; i += stride) {
    const int elem = i << 2;
    const int row = elem >> 9;          // DIM = 512
    const int c4 = (elem & 511) >> 2;   // float4 index within row
    const int rr = (row >> 8) - br;
    const int cc = (row & 255) - bc;
    const float d2 = (float)(rr * rr + cc * cc);
    const float mult = alpha_op * __expf(-d2 * inv_s2);

    f32x4 wv = w4[i];
    f32x4 iv = in4[c4];
    f32x4 r = wv + mult * (iv - wv);
    f32x2 a; a.x = r.x; a.y = r.y;
    f32x2 b; b.x = r.z; b.y = r.w;
    o2[2 * i] = a;
    o2[2 * i + 1] = b;
  }
}

extern "C" void kernel_launch(void* const* d_in, const int* in_sizes, int n_in,
                              void* d_out, int out_size, void* d_ws, size_t ws_size,
                              hipStream_t stream) {
  const float* input_vector = (const float*)d_in[0];
  const float* weights = (const float*)d_in[1];
  const int* epoch = (const int*)d_in[2];
  float* out = (float*)d_out;

  unsigned long long* part = (unsigned long long*)d_ws;  // [NB]

  som_bmu_partial<<<NB, 256, 0, stream>>>(weights, input_vector, part);
  som_update<<<NB, 256, 0, stream>>>(weights, input_vector, epoch, part, out);
}

// Round 4
// 69.083 us; speedup vs baseline: 1.3317x; 1.0257x over previous
//
#include <hip/hip_runtime.h>

// Problem constants (from reference)
#define SOM_M 256
#define SOM_N 256
#define SOM_DIM 512
#define SOM_ROWS (SOM_M * SOM_N)          // 65536
#define SOM_ELEMS (SOM_ROWS * SOM_DIM)    // 33554432
#define NB 2048                           // blocks for both kernels

typedef float f32x4 __attribute__((ext_vector_type(4)));
typedef float f32x2 __attribute__((ext_vector_type(2)));

// ---------------- Kernel 1: per-block BMU partial argmin ----------------
// One wave (64 lanes) per row; lane loads 8 floats (2x float4), butterfly
// reduce sum of squared diffs; block writes packed (dist|idx) u64 partial.
// dist >= 0 so float bits are monotone as u32; equal dist -> smaller row
// wins, matching jnp.argmin first-occurrence semantics.
__global__ __launch_bounds__(256) void som_bmu_partial(
    const float* __restrict__ w, const float* __restrict__ in,
    unsigned long long* __restrict__ part) {
  __shared__ float s_in[SOM_DIM];
  for (int i = threadIdx.x; i < SOM_DIM; i += 256) s_in[i] = in[i];
  __syncthreads();

  const int wave = threadIdx.x >> 6;
  const int lane = threadIdx.x & 63;
  const int globalWave = blockIdx.x * 4 + wave;
  const int nWaves = NB * 4;

  float bd = 3.4e38f;
  int bi = SOM_ROWS;

  const f32x4* in4 = (const f32x4*)s_in;
  for (int row = globalWave; row < SOM_ROWS; row += nWaves) {
    const f32x4* wr = (const f32x4*)(w + (size_t)row * SOM_DIM);
    float acc = 0.f;
#pragma unroll
    for (int k = 0; k < 2; ++k) {
      f32x4 wv = wr[lane + 64 * k];
      f32x4 iv = in4[lane + 64 * k];
      f32x4 d = wv - iv;
      acc += d.x * d.x + d.y * d.y + d.z * d.z + d.w * d.w;
    }
#pragma unroll
    for (int off = 32; off; off >>= 1) acc += __shfl_xor(acc, off, 64);
    // rows visited in increasing order per wave -> strict < keeps first min
    if (acc < bd) { bd = acc; bi = row; }
  }

  unsigned long long pk =
      ((unsigned long long)__float_as_uint(bd) << 32) | (unsigned int)bi;

  __shared__ unsigned long long sp[4];
  if (lane == 0) sp[wave] = pk;
  __syncthreads();
  if (threadIdx.x == 0) {
    unsigned long long m = sp[0];
#pragma unroll
    for (int k = 1; k < 4; ++k) m = (sp[k] < m) ? sp[k] : m;
    part[blockIdx.x] = m;
  }
}

// ---------------- Kernel 2: inline final reduce + weight update ----------------
// Each block first min-reduces the NB packed partials (L2-resident, ~16KB),
// then: new_w = w + alpha_op * exp(-bmu_dist_sq / sigma_op^2) * (in - w)
// Processing is symmetric at f32x2 granularity so BOTH the weight loads and
// the (out+2)-offset stores are fully contiguous per wave-instruction.
__global__ __launch_bounds__(256) void som_update(
    const float* __restrict__ w, const float* __restrict__ in,
    const int* __restrict__ epoch_p,
    const unsigned long long* __restrict__ part,
    float* __restrict__ out /* d_out base */) {
  // --- final argmin reduce (all blocks, redundant but cheap) ---
  __shared__ unsigned long long sp[256];
  unsigned long long m = ~0ull;
  for (int i = threadIdx.x; i < NB; i += 256) {
    unsigned long long v = part[i];
    m = (v < m) ? v : m;
  }
  sp[threadIdx.x] = m;
  __syncthreads();
  for (int s = 128; s; s >>= 1) {
    if ((int)threadIdx.x < s) {
      if (sp[threadIdx.x + s] < sp[threadIdx.x]) sp[threadIdx.x] = sp[threadIdx.x + s];
    }
    __syncthreads();
  }
  const int bidx = (int)(unsigned int)(sp[0] & 0xFFFFFFFFull);
  const int br = bidx >> 8;   // N = 256
  const int bc = bidx & 255;

  if (blockIdx.x == 0 && threadIdx.x == 0) {
    out[0] = (float)br;
    out[1] = (float)bc;
  }

  const float lr = 1.0f - (float)epoch_p[0] / 100.0f;
  const float alpha_op = 0.3f * lr;
  const float sigma_op = 128.0f * lr;
  const float inv_s2 = 1.0f / (sigma_op * sigma_op);

  const f32x2* w2 = (const f32x2*)w;
  const f32x2* in2 = (const f32x2*)in;
  f32x2* o2 = (f32x2*)(out + 2);  // 8B-aligned

  const int total2 = SOM_ELEMS / 2;  // 16777216
  const int stride = NB * 256;
  for (int j = blockIdx.x * 256 + threadIdx.x; j < total2; j += stride) {
    const int row = j >> 8;             // element e = 2j, row = e >> 9
    const int rr = (row >> 8) - br;
    const int cc = (row & 255) - bc;
    const float d2 = (float)(rr * rr + cc * cc);
    const float mult = alpha_op * __expf(-d2 * inv_s2);

    f32x2 wv = w2[j];
    f32x2 iv = in2[j & 255];
    f32x2 r = wv + mult * (iv - wv);
    o2[j] = r;
  }
}

extern "C" void kernel_launch(void* const* d_in, const int* in_sizes, int n_in,
                              void* d_out, int out_size, void* d_ws, size_t ws_size,
                              hipStream_t stream) {
  const float* input_vector = (const float*)d_in[0];
  const float* weights = (const float*)d_in[1];
  const int* epoch = (const int*)d_in[2];
  float* out = (float*)d_out;

  unsigned long long* part = (unsigned long long*)d_ws;  // [NB]

  som_bmu_partial<<<NB, 256, 0, stream>>>(weights, input_vector, part);
  som_update<<<NB, 256, 0, stream>>>(weights, input_vector, epoch, part, out);
}